// Round 2
// baseline (169.829 us; speedup 1.0000x reference)
//
#include <hip/hip_runtime.h>
#include <hip/hip_bf16.h>

typedef __attribute__((ext_vector_type(8))) short  bf16x8;
typedef __attribute__((ext_vector_type(4))) float  f32x4;
typedef __attribute__((ext_vector_type(4))) int    i32x4;

#define B_   8
#define R_   4
#define N_   2048
#define S_   6
#define DIN  32
#define DOUT 32

// ---------------------------------------------------------------------------
// Pre-kernel: XW_T[b][r][e][perm(m)] = bf16( coef[r] * sum_d X[b,r,m,d] * fc_w[r,d,e] )
// coef[r] = sum_s theta[r,s]*t[r,s].
//
// K-PERMUTATION: the main GEMM is invariant under a permutation of K applied
// to both operands. We pick, within each 32-k chunk,
//     logical slot (kg, j)  <->  actual k = (j>=4)*16 + kg*4 + (j&3)
// so the main kernel's A-fragment load (lane kg reads 16B at kg*16) covers a
// full contiguous 64B line per A row per instruction (perfect coalescing),
// instead of 16B-used-per-32B-stride scatter. XW_T absorbs the permutation
// here at store time:  pos(m) within chunk = kg*8 + s*4 + (m&3),
// kg=(m>>2)&3, s=(m>>4)&1.
// ---------------------------------------------------------------------------
__global__ __launch_bounds__(256) void prep_xw(
    const float* __restrict__ theta, const float* __restrict__ tpar,
    const float* __restrict__ X,     const float* __restrict__ fcw,
    __hip_bfloat16* __restrict__ xwt)
{
    int br    = blockIdx.x >> 5;      // b*4 + r   (32 of them)
    int mtile = blockIdx.x & 31;      // N/64 = 32 m-tiles
    int r     = br & 3;
    int t     = threadIdx.x;
    int m     = mtile * 64 + (t & 63);
    int egrp  = t >> 6;               // 0..3

    float coef = 0.f;
#pragma unroll
    for (int s = 0; s < S_; ++s) coef += theta[r * S_ + s] * tpar[r * S_ + s];

    const float* xrow = X + ((size_t)br * N_ + m) * DIN;
    float xr[DIN];
#pragma unroll
    for (int i = 0; i < DIN / 4; ++i) {
        f32x4 v = *(const f32x4*)(xrow + i * 4);
        xr[i * 4 + 0] = v.x; xr[i * 4 + 1] = v.y;
        xr[i * 4 + 2] = v.z; xr[i * 4 + 3] = v.w;
    }

    // permuted store position for this m
    int m5  = m & 31;
    int pos = (m & ~31) + (((m5 >> 2) & 3) << 3) + ((m5 >> 4) << 2) + (m5 & 3);

#pragma unroll
    for (int eb = 0; eb < 8; ++eb) {
        int e = egrp * 8 + eb;
        float acc = 0.f;
#pragma unroll
        for (int d = 0; d < DIN; ++d) acc += xr[d] * fcw[(r * DIN + d) * DOUT + e];
        xwt[((size_t)br * DOUT + e) * N_ + pos] = __float2bfloat16(coef * acc);
    }
}

// ---------------------------------------------------------------------------
// Main fused kernel: per (b, 16-row n-tile) block, 4 waves (one per relation).
//   acc = A(bf16) x XW_T(bf16) via mfma_f32_16x16x32_bf16, K=2048
//   A loads use the permuted-k fragment mapping: lane (row16, kg) reads
//   a0 = A[row][kt*32 + kg*4 .. +4)   (bytes kt*128 + kg*16  -> full 64B line/row)
//   a1 = A[row][kt*32 + 16 + kg*4 ..) (bytes kt*128 + 64 + kg*16)
//   epilogue: +fc_b, prelu0, 4x4 conv mix across r (LDS), +conv_b, prelu1.
// ---------------------------------------------------------------------------
__global__ __launch_bounds__(256) void fused_main(
    const float* __restrict__ A,   const __hip_bfloat16* __restrict__ xwt,
    const float* __restrict__ fcb, const float* __restrict__ cw,
    const float* __restrict__ cb,  const float* __restrict__ p0p,
    const float* __restrict__ p1p, float* __restrict__ out)
{
    __shared__ float hlds[R_][16][DOUT + 1];   // +1 pad: bank-conflict-free

    // chunked XCD swizzle: XCD x gets logical blocks [x*128, (x+1)*128) — one
    // batch b per XCD, so each XCD's L2 holds one 512KB xwt slice.
    int bid  = blockIdx.x;
    int swz  = (bid & 7) * 128 + (bid >> 3);
    int b    = swz >> 7;            // 8 batches
    int tile = swz & 127;           // 128 n-tiles of 16
    int n0   = tile * 16;
    int t    = threadIdx.x;
    int r    = t >> 6;              // wave = relation
    int l    = t & 63;
    int row16 = l & 15;             // M row within tile (A frag), e col (B frag)
    int kg    = l >> 4;             // k-group 0..3

    const float* Arow = A + (((size_t)(b * R_ + r)) * N_ + (n0 + row16)) * N_;
    const float* Ap0  = Arow + kg * 4;        // j=0..3  (actual k = kg*4+{0..3})
    const float* Ap1  = Arow + 16 + kg * 4;   // j=4..7  (actual k = 16+kg*4+{0..3})

    const ushort* xw  = (const ushort*)xwt + ((size_t)(b * R_ + r) * DOUT) * N_;
    const ushort* xw0 = xw + (size_t)row16 * N_        + kg * 8;
    const ushort* xw1 = xw + (size_t)(16 + row16) * N_ + kg * 8;

    f32x4 acc0 = {0.f, 0.f, 0.f, 0.f};
    f32x4 acc1 = {0.f, 0.f, 0.f, 0.f};

#pragma unroll 4
    for (int kt = 0; kt < N_ / 32; ++kt) {
        f32x4 a0 = *(const f32x4*)(Ap0 + kt * 32);
        f32x4 a1 = *(const f32x4*)(Ap1 + kt * 32);
        i32x4 bv0 = *(const i32x4*)(xw0 + kt * 32);
        i32x4 bv1 = *(const i32x4*)(xw1 + kt * 32);
        i32x4 av;
        asm("v_cvt_pk_bf16_f32 %0, %1, %2" : "=v"(av.x) : "v"(a0.x), "v"(a0.y));
        asm("v_cvt_pk_bf16_f32 %0, %1, %2" : "=v"(av.y) : "v"(a0.z), "v"(a0.w));
        asm("v_cvt_pk_bf16_f32 %0, %1, %2" : "=v"(av.z) : "v"(a1.x), "v"(a1.y));
        asm("v_cvt_pk_bf16_f32 %0, %1, %2" : "=v"(av.w) : "v"(a1.z), "v"(a1.w));
        bf16x8 af = __builtin_bit_cast(bf16x8, av);
        bf16x8 b0 = __builtin_bit_cast(bf16x8, bv0);
        bf16x8 b1 = __builtin_bit_cast(bf16x8, bv1);
        acc0 = __builtin_amdgcn_mfma_f32_16x16x32_bf16(af, b0, acc0, 0, 0, 0);
        acc1 = __builtin_amdgcn_mfma_f32_16x16x32_bf16(af, b1, acc1, 0, 0, 0);
    }

    float p0 = p0p[0], p1 = p1p[0];

    // fc bias + prelu0 -> LDS  (C layout: row = kg*4+j, col = row16 / 16+row16)
#pragma unroll
    for (int j = 0; j < 4; ++j) {
        int rw = kg * 4 + j;
        float v0 = acc0[j] + fcb[r * DOUT + row16];
        float v1 = acc1[j] + fcb[r * DOUT + 16 + row16];
        hlds[r][rw][row16]      = v0 >= 0.f ? v0 : p0 * v0;
        hlds[r][rw][16 + row16] = v1 >= 0.f ? v1 : p0 * v1;
    }
    __syncthreads();

    // conv mix across relations: wave r produces output channel q = r
    int q = r;
    float c0 = cw[q * R_ + 0], c1 = cw[q * R_ + 1];
    float c2 = cw[q * R_ + 2], c3 = cw[q * R_ + 3];
    float cbq = cb[q];
    int e  = l & 31;
    int rg = l >> 5;
#pragma unroll
    for (int i = 0; i < 8; ++i) {
        int row = rg * 8 + i;
        float mx = cbq + c0 * hlds[0][row][e] + c1 * hlds[1][row][e]
                       + c2 * hlds[2][row][e] + c3 * hlds[3][row][e];
        float lat = mx >= 0.f ? mx : p1 * mx;
        out[(((size_t)b * R_ + q) * N_ + (n0 + row)) * DOUT + e] = lat;
    }
}

extern "C" void kernel_launch(void* const* d_in, const int* in_sizes, int n_in,
                              void* d_out, int out_size, void* d_ws, size_t ws_size,
                              hipStream_t stream)
{
    const float* theta = (const float*)d_in[0];
    const float* tpar  = (const float*)d_in[1];
    const float* A     = (const float*)d_in[2];
    const float* X     = (const float*)d_in[3];
    const float* fcw   = (const float*)d_in[4];
    const float* fcb   = (const float*)d_in[5];
    const float* cw    = (const float*)d_in[6];
    const float* cb    = (const float*)d_in[7];
    const float* p0    = (const float*)d_in[8];
    const float* p1    = (const float*)d_in[9];

    __hip_bfloat16* xwt = (__hip_bfloat16*)d_ws;   // 8*4*32*2048*2B = 4 MiB

    prep_xw<<<B_ * R_ * (N_ / 64), 256, 0, stream>>>(theta, tpar, X, fcw, xwt);
    fused_main<<<B_ * (N_ / 16), 256, 0, stream>>>(A, xwt, fcb, cw, cb, p0, p1,
                                                   (float*)d_out);
}

// Round 3
// 140.615 us; speedup vs baseline: 1.2078x; 1.2078x over previous
//
#include <hip/hip_runtime.h>
#include <hip/hip_bf16.h>

typedef __attribute__((ext_vector_type(8))) short  bf16x8;
typedef __attribute__((ext_vector_type(4))) float  f32x4;
typedef __attribute__((ext_vector_type(4))) int    i32x4;
typedef __attribute__((address_space(3))) void       as3void;
typedef const __attribute__((address_space(1))) void as1void;

#define B_   8
#define R_   4
#define N_   2048
#define S_   6
#define DIN  32
#define DOUT 32
#define NT   32    // K-steps of BK=64

// ---------------------------------------------------------------------------
// Pre-kernel (R1 version, contiguous stores):
// XW_T[b][r][e][m] = bf16( coef[r] * sum_d X[b,r,m,d] * fc_w[r,d,e] )
// ---------------------------------------------------------------------------
__global__ __launch_bounds__(256) void prep_xw(
    const float* __restrict__ theta, const float* __restrict__ tpar,
    const float* __restrict__ X,     const float* __restrict__ fcw,
    __hip_bfloat16* __restrict__ xwt)
{
    int br    = blockIdx.x >> 5;
    int mtile = blockIdx.x & 31;
    int r     = br & 3;
    int t     = threadIdx.x;
    int m     = mtile * 64 + (t & 63);
    int egrp  = t >> 6;

    float coef = 0.f;
#pragma unroll
    for (int s = 0; s < S_; ++s) coef += theta[r * S_ + s] * tpar[r * S_ + s];

    const float* xrow = X + ((size_t)br * N_ + m) * DIN;
    float xr[DIN];
#pragma unroll
    for (int i = 0; i < DIN / 4; ++i) {
        f32x4 v = *(const f32x4*)(xrow + i * 4);
        xr[i * 4 + 0] = v.x; xr[i * 4 + 1] = v.y;
        xr[i * 4 + 2] = v.z; xr[i * 4 + 3] = v.w;
    }
#pragma unroll
    for (int eb = 0; eb < 8; ++eb) {
        int e = egrp * 8 + eb;
        float acc = 0.f;
#pragma unroll
        for (int d = 0; d < DIN; ++d) acc += xr[d] * fcw[(r * DIN + d) * DOUT + e];
        xwt[((size_t)br * DOUT + e) * N_ + m] = __float2bfloat16(coef * acc);
    }
}

// ---------------------------------------------------------------------------
// Main fused kernel. 4 waves/block (wave r = relation r), 16-row n-tile.
// A (f32, HBM) is staged per-wave into private LDS via global_load_lds DMA,
// double-buffered, counted vmcnt(8) — no barriers in the K-loop.
// XOR swizzle (row&7)<<4 folded into the per-lane DMA SOURCE address (G21),
// applied again on ds_read -> conflict-free b128 fragment reads.
// B (bf16 xwt, L2-resident) loaded to VGPRs via volatile asm (exact vmcnt).
// ---------------------------------------------------------------------------
__global__ __launch_bounds__(256) void fused_main(
    const float* __restrict__ A,   const __hip_bfloat16* __restrict__ xwt,
    const float* __restrict__ fcb, const float* __restrict__ cw,
    const float* __restrict__ cb,  const float* __restrict__ p0p,
    const float* __restrict__ p1p, float* __restrict__ out)
{
    __shared__ char smem[32768];   // [buf(2)][wave(4)][16 rows][64 k] f32

    int b    = blockIdx.x >> 7;
    int tile = blockIdx.x & 127;
    int n0   = tile * 16;
    int t    = threadIdx.x;
    int r    = t >> 6;
    int l    = t & 63;
    int row16 = l & 15;
    int kg    = l >> 4;
    int swzr  = (row16 & 7) << 4;
    int ldsbase = r * 4096;

    // per-lane DMA source pointers (swizzle pre-applied; kt adds multiples of 256B)
    const char* Ab = (const char*)(A + (((size_t)(b * R_ + r)) * N_ + n0) * N_);
    const char* srcp[4];
#pragma unroll
    for (int i = 0; i < 4; ++i) {
        int row = i * 4 + kg;
        srcp[i] = Ab + (size_t)row * (N_ * 4) + (((l & 15) * 16) ^ ((row & 7) << 4));
    }

    // B pointers: bp[eh*2+m] -> element (eh*16+row16)*N + m*32 + kg*8
    const ushort* xw = (const ushort*)xwt + (size_t)(b * R_ + r) * DOUT * N_;
    const ushort* bp[4];
#pragma unroll
    for (int eh = 0; eh < 2; ++eh)
#pragma unroll
        for (int m = 0; m < 2; ++m)
            bp[eh * 2 + m] = xw + (size_t)(eh * 16 + row16) * N_ + m * 32 + kg * 8;

#define STAGE_A(CUR, KT) do {                                                   \
    _Pragma("unroll")                                                           \
    for (int i_ = 0; i_ < 4; ++i_) {                                            \
        __builtin_amdgcn_global_load_lds(                                       \
            (as1void*)(srcp[i_] + (KT) * 256),                                  \
            (as3void*)&smem[(CUR) * 16384 + ldsbase + i_ * 1024], 16, 0, 0);    \
    } } while (0)

#define LOADB(D0, D1, D2, D3, KT) do {                                          \
    asm volatile("global_load_dwordx4 %0, %1, off" : "=v"(D0) : "v"(bp[0] + (KT) * 64)); \
    asm volatile("global_load_dwordx4 %0, %1, off" : "=v"(D1) : "v"(bp[1] + (KT) * 64)); \
    asm volatile("global_load_dwordx4 %0, %1, off" : "=v"(D2) : "v"(bp[2] + (KT) * 64)); \
    asm volatile("global_load_dwordx4 %0, %1, off" : "=v"(D3) : "v"(bp[3] + (KT) * 64)); \
    } while (0)

    f32x4 acc0 = {0.f, 0.f, 0.f, 0.f};
    f32x4 acc1 = {0.f, 0.f, 0.f, 0.f};
    i32x4 bc0, bc1, bc2, bc3, bn0, bn1, bn2, bn3;

    STAGE_A(0, 0);
    LOADB(bc0, bc1, bc2, bc3, 0);

#pragma unroll 2
    for (int kt = 0; kt < NT; ++kt) {
        int cur = kt & 1;
        __builtin_amdgcn_sched_barrier(0);   // prev compute may not sink past next stage
        if (kt < NT - 1) {
            STAGE_A(cur ^ 1, kt + 1);
            LOADB(bn0, bn1, bn2, bn3, kt + 1);
            __builtin_amdgcn_sched_barrier(0);
            asm volatile("s_waitcnt vmcnt(8)" ::: "memory");  // cur's 8 loads done
        } else {
            __builtin_amdgcn_sched_barrier(0);
            asm volatile("s_waitcnt vmcnt(0)" ::: "memory");
        }
        __builtin_amdgcn_sched_barrier(0);

        {   // COMPUTE on buf[cur]
            const char* abuf = &smem[cur * 16384 + ldsbase];
            int base = row16 * 256 + kg * 32;
            f32x4 lo0 = *(const f32x4*)(abuf + ((base +   0 +  0) ^ swzr));
            f32x4 hi0 = *(const f32x4*)(abuf + ((base +   0 + 16) ^ swzr));
            f32x4 lo1 = *(const f32x4*)(abuf + ((base + 128 +  0) ^ swzr));
            f32x4 hi1 = *(const f32x4*)(abuf + ((base + 128 + 16) ^ swzr));
            i32x4 av0, av1;
            asm("v_cvt_pk_bf16_f32 %0, %1, %2" : "=v"(av0.x) : "v"(lo0.x), "v"(lo0.y));
            asm("v_cvt_pk_bf16_f32 %0, %1, %2" : "=v"(av0.y) : "v"(lo0.z), "v"(lo0.w));
            asm("v_cvt_pk_bf16_f32 %0, %1, %2" : "=v"(av0.z) : "v"(hi0.x), "v"(hi0.y));
            asm("v_cvt_pk_bf16_f32 %0, %1, %2" : "=v"(av0.w) : "v"(hi0.z), "v"(hi0.w));
            asm("v_cvt_pk_bf16_f32 %0, %1, %2" : "=v"(av1.x) : "v"(lo1.x), "v"(lo1.y));
            asm("v_cvt_pk_bf16_f32 %0, %1, %2" : "=v"(av1.y) : "v"(lo1.z), "v"(lo1.w));
            asm("v_cvt_pk_bf16_f32 %0, %1, %2" : "=v"(av1.z) : "v"(hi1.x), "v"(hi1.y));
            asm("v_cvt_pk_bf16_f32 %0, %1, %2" : "=v"(av1.w) : "v"(hi1.z), "v"(hi1.w));
            bf16x8 a0 = __builtin_bit_cast(bf16x8, av0);
            bf16x8 a1 = __builtin_bit_cast(bf16x8, av1);
            acc0 = __builtin_amdgcn_mfma_f32_16x16x32_bf16(a0, __builtin_bit_cast(bf16x8, bc0), acc0, 0, 0, 0);
            acc0 = __builtin_amdgcn_mfma_f32_16x16x32_bf16(a1, __builtin_bit_cast(bf16x8, bc1), acc0, 0, 0, 0);
            acc1 = __builtin_amdgcn_mfma_f32_16x16x32_bf16(a0, __builtin_bit_cast(bf16x8, bc2), acc1, 0, 0, 0);
            acc1 = __builtin_amdgcn_mfma_f32_16x16x32_bf16(a1, __builtin_bit_cast(bf16x8, bc3), acc1, 0, 0, 0);
        }
        bc0 = bn0; bc1 = bn1; bc2 = bn2; bc3 = bn3;
    }
#undef STAGE_A
#undef LOADB

    float p0 = p0p[0], p1 = p1p[0];

    __syncthreads();   // all waves done with Abuf before hlds overlays smem
    float (*hlds)[16][DOUT + 1] = (float (*)[16][DOUT + 1])(void*)smem;
#pragma unroll
    for (int j = 0; j < 4; ++j) {
        int rw = kg * 4 + j;
        float v0 = acc0[j] + fcb[r * DOUT + row16];
        float v1 = acc1[j] + fcb[r * DOUT + 16 + row16];
        hlds[r][rw][row16]      = v0 >= 0.f ? v0 : p0 * v0;
        hlds[r][rw][16 + row16] = v1 >= 0.f ? v1 : p0 * v1;
    }
    __syncthreads();

    int q = r;
    float c0 = cw[q * R_ + 0], c1 = cw[q * R_ + 1];
    float c2 = cw[q * R_ + 2], c3 = cw[q * R_ + 3];
    float cbq = cb[q];
    int e  = l & 31;
    int rg = l >> 5;
#pragma unroll
    for (int i = 0; i < 8; ++i) {
        int row = rg * 8 + i;
        float mx = cbq + c0 * hlds[0][row][e] + c1 * hlds[1][row][e]
                       + c2 * hlds[2][row][e] + c3 * hlds[3][row][e];
        float lat = mx >= 0.f ? mx : p1 * mx;
        out[(((size_t)b * R_ + q) * N_ + (n0 + row)) * DOUT + e] = lat;
    }
}

extern "C" void kernel_launch(void* const* d_in, const int* in_sizes, int n_in,
                              void* d_out, int out_size, void* d_ws, size_t ws_size,
                              hipStream_t stream)
{
    const float* theta = (const float*)d_in[0];
    const float* tpar  = (const float*)d_in[1];
    const float* A     = (const float*)d_in[2];
    const float* X     = (const float*)d_in[3];
    const float* fcw   = (const float*)d_in[4];
    const float* fcb   = (const float*)d_in[5];
    const float* cw    = (const float*)d_in[6];
    const float* cb    = (const float*)d_in[7];
    const float* p0    = (const float*)d_in[8];
    const float* p1    = (const float*)d_in[9];

    __hip_bfloat16* xwt = (__hip_bfloat16*)d_ws;   // 4 MiB

    prep_xw<<<B_ * R_ * (N_ / 64), 256, 0, stream>>>(theta, tpar, X, fcw, xwt);
    fused_main<<<B_ * (N_ / 16), 256, 0, stream>>>(A, xwt, fcb, cw, cb, p0, p1,
                                                   (float*)d_out);
}

// Round 4
// 138.555 us; speedup vs baseline: 1.2257x; 1.0149x over previous
//
#include <hip/hip_runtime.h>
#include <hip/hip_bf16.h>

typedef __attribute__((ext_vector_type(8))) short  bf16x8;
typedef __attribute__((ext_vector_type(4))) float  f32x4;
typedef __attribute__((ext_vector_type(4))) int    i32x4;
typedef __attribute__((address_space(3))) void       as3void;
typedef const __attribute__((address_space(1))) void as1void;

#define B_   8
#define R_   4
#define N_   2048
#define S_   6
#define DIN  32
#define DOUT 32
#define NT   16    // K-supertiles of BK=128

// ---------------------------------------------------------------------------
// Pre-kernel: XW_T[b][r][e][m] = bf16( coef[r] * sum_d X[b,r,m,d] * fc_w[r,d,e] )
// ---------------------------------------------------------------------------
__global__ __launch_bounds__(256) void prep_xw(
    const float* __restrict__ theta, const float* __restrict__ tpar,
    const float* __restrict__ X,     const float* __restrict__ fcw,
    __hip_bfloat16* __restrict__ xwt)
{
    int br    = blockIdx.x >> 5;
    int mtile = blockIdx.x & 31;
    int r     = br & 3;
    int t     = threadIdx.x;
    int m     = mtile * 64 + (t & 63);
    int egrp  = t >> 6;

    float coef = 0.f;
#pragma unroll
    for (int s = 0; s < S_; ++s) coef += theta[r * S_ + s] * tpar[r * S_ + s];

    const float* xrow = X + ((size_t)br * N_ + m) * DIN;
    float xr[DIN];
#pragma unroll
    for (int i = 0; i < DIN / 4; ++i) {
        f32x4 v = *(const f32x4*)(xrow + i * 4);
        xr[i * 4 + 0] = v.x; xr[i * 4 + 1] = v.y;
        xr[i * 4 + 2] = v.z; xr[i * 4 + 3] = v.w;
    }
#pragma unroll
    for (int eb = 0; eb < 8; ++eb) {
        int e = egrp * 8 + eb;
        float acc = 0.f;
#pragma unroll
        for (int d = 0; d < DIN; ++d) acc += xr[d] * fcw[(r * DIN + d) * DOUT + e];
        xwt[((size_t)br * DOUT + e) * N_ + m] = __float2bfloat16(coef * acc);
    }
}

// ---------------------------------------------------------------------------
// Main fused kernel. 4 waves/block (wave r = relation r), 16-row n-tile.
// A staged per-wave into private LDS via global_load_lds DMA in 512B-per-row
// chunks (BK=128 supertile: 8 instrs, each 2 rows x 512B contiguous),
// double-buffered, counted vmcnt(16) — no barriers in the K-loop.
// XOR swizzle ((row&7)<<4) pre-applied to DMA SOURCE (linear dest, G21);
// same XOR on ds_read -> conflict-free b128 fragment reads.
// B (bf16 xwt, L2-resident) in VGPRs via volatile asm (exact vmcnt count).
// ---------------------------------------------------------------------------
__global__ __launch_bounds__(256) void fused_main(
    const float* __restrict__ A,   const __hip_bfloat16* __restrict__ xwt,
    const float* __restrict__ fcb, const float* __restrict__ cw,
    const float* __restrict__ cb,  const float* __restrict__ p0p,
    const float* __restrict__ p1p, float* __restrict__ out)
{
    __shared__ char smem[65536];   // [buf(2)][wave(4)][16 rows][128 k f32] = 2*4*8KB

    int b    = blockIdx.x >> 7;
    int tile = blockIdx.x & 127;
    int n0   = tile * 16;
    int t    = threadIdx.x;
    int r    = t >> 6;
    int l    = t & 63;
    int row16 = l & 15;
    int kg    = l >> 4;
    int swzr  = (row16 & 7) << 4;
    int ldsbase = r * 8192;
    int hl   = l >> 5;    // staging: lane half selects row parity
    int l31  = l & 31;

    // per-lane DMA source pointers: instr i covers rows {2i, 2i+1} x 512B,
    // swizzle pre-applied within each row's 512B run.
    const char* Ab = (const char*)(A + (((size_t)(b * R_ + r)) * N_ + n0) * N_);
    const char* srcp[8];
#pragma unroll
    for (int i = 0; i < 8; ++i) {
        int row = 2 * i + hl;
        srcp[i] = Ab + (size_t)row * (N_ * 4) + ((l31 * 16) ^ ((row & 7) << 4));
    }

    // B pointers: fragment (e = eh*16+row16, k = kt*128 + ks*32 + kg*8)
    const ushort* xw  = (const ushort*)xwt + (size_t)(b * R_ + r) * DOUT * N_;
    const ushort* bp0 = xw + (size_t)row16 * N_        + kg * 8;
    const ushort* bp1 = xw + (size_t)(16 + row16) * N_ + kg * 8;

#define STAGE_A(CUR, KT) do {                                                    \
    _Pragma("unroll")                                                            \
    for (int i_ = 0; i_ < 8; ++i_) {                                             \
        __builtin_amdgcn_global_load_lds(                                        \
            (as1void*)(srcp[i_] + (size_t)(KT) * 512),                           \
            (as3void*)&smem[(CUR) * 32768 + ldsbase + i_ * 1024], 16, 0, 0);     \
    } } while (0)

#define LOADB(P, KT) do {                                                        \
    asm volatile("global_load_dwordx4 %0, %1, off" : "=v"(P##0) : "v"(bp0 + (KT) * 128 +  0)); \
    asm volatile("global_load_dwordx4 %0, %1, off" : "=v"(P##1) : "v"(bp0 + (KT) * 128 + 32)); \
    asm volatile("global_load_dwordx4 %0, %1, off" : "=v"(P##2) : "v"(bp0 + (KT) * 128 + 64)); \
    asm volatile("global_load_dwordx4 %0, %1, off" : "=v"(P##3) : "v"(bp0 + (KT) * 128 + 96)); \
    asm volatile("global_load_dwordx4 %0, %1, off" : "=v"(P##4) : "v"(bp1 + (KT) * 128 +  0)); \
    asm volatile("global_load_dwordx4 %0, %1, off" : "=v"(P##5) : "v"(bp1 + (KT) * 128 + 32)); \
    asm volatile("global_load_dwordx4 %0, %1, off" : "=v"(P##6) : "v"(bp1 + (KT) * 128 + 64)); \
    asm volatile("global_load_dwordx4 %0, %1, off" : "=v"(P##7) : "v"(bp1 + (KT) * 128 + 96)); \
    } while (0)

    f32x4 acc0 = {0.f, 0.f, 0.f, 0.f};
    f32x4 acc1 = {0.f, 0.f, 0.f, 0.f};
    i32x4 bc0, bc1, bc2, bc3, bc4, bc5, bc6, bc7;
    i32x4 bn0, bn1, bn2, bn3, bn4, bn5, bn6, bn7;

    STAGE_A(0, 0);
    LOADB(bc, 0);

#pragma unroll 2
    for (int kt = 0; kt < NT; ++kt) {
        int cur = kt & 1;
        __builtin_amdgcn_sched_barrier(0);
        if (kt < NT - 1) {
            STAGE_A(cur ^ 1, kt + 1);
            LOADB(bn, kt + 1);
            __builtin_amdgcn_sched_barrier(0);
            asm volatile("s_waitcnt vmcnt(16)" ::: "memory");  // cur's 16 done
        } else {
            __builtin_amdgcn_sched_barrier(0);
            asm volatile("s_waitcnt vmcnt(0)" ::: "memory");
        }
        __builtin_amdgcn_sched_barrier(0);

        {   // COMPUTE on buf[cur]: 4 MFMA k-steps of 32
            const char* abuf = &smem[cur * 32768 + ldsbase];
            int rbase = row16 * 512;
#define KSTEP(KS, BA, BB) do {                                                   \
    f32x4 lo = *(const f32x4*)(abuf + rbase + (((KS) * 128 + kg * 32 +  0) ^ swzr)); \
    f32x4 hi = *(const f32x4*)(abuf + rbase + (((KS) * 128 + kg * 32 + 16) ^ swzr)); \
    i32x4 av;                                                                    \
    asm("v_cvt_pk_bf16_f32 %0, %1, %2" : "=v"(av.x) : "v"(lo.x), "v"(lo.y));     \
    asm("v_cvt_pk_bf16_f32 %0, %1, %2" : "=v"(av.y) : "v"(lo.z), "v"(lo.w));     \
    asm("v_cvt_pk_bf16_f32 %0, %1, %2" : "=v"(av.z) : "v"(hi.x), "v"(hi.y));     \
    asm("v_cvt_pk_bf16_f32 %0, %1, %2" : "=v"(av.w) : "v"(hi.z), "v"(hi.w));     \
    bf16x8 af = __builtin_bit_cast(bf16x8, av);                                  \
    acc0 = __builtin_amdgcn_mfma_f32_16x16x32_bf16(af, __builtin_bit_cast(bf16x8, BA), acc0, 0, 0, 0); \
    acc1 = __builtin_amdgcn_mfma_f32_16x16x32_bf16(af, __builtin_bit_cast(bf16x8, BB), acc1, 0, 0, 0); \
    } while (0)
            KSTEP(0, bc0, bc4);
            KSTEP(1, bc1, bc5);
            KSTEP(2, bc2, bc6);
            KSTEP(3, bc3, bc7);
#undef KSTEP
        }
        bc0 = bn0; bc1 = bn1; bc2 = bn2; bc3 = bn3;
        bc4 = bn4; bc5 = bn5; bc6 = bn6; bc7 = bn7;
    }
#undef STAGE_A
#undef LOADB

    float p0 = p0p[0], p1 = p1p[0];

    __syncthreads();   // all waves done with A buffers before hlds overlays smem
    float (*hlds)[16][DOUT + 1] = (float (*)[16][DOUT + 1])(void*)smem;
#pragma unroll
    for (int j = 0; j < 4; ++j) {
        int rw = kg * 4 + j;
        float v0 = acc0[j] + fcb[r * DOUT + row16];
        float v1 = acc1[j] + fcb[r * DOUT + 16 + row16];
        hlds[r][rw][row16]      = v0 >= 0.f ? v0 : p0 * v0;
        hlds[r][rw][16 + row16] = v1 >= 0.f ? v1 : p0 * v1;
    }
    __syncthreads();

    int q = r;
    float c0 = cw[q * R_ + 0], c1 = cw[q * R_ + 1];
    float c2 = cw[q * R_ + 2], c3 = cw[q * R_ + 3];
    float cbq = cb[q];
    int e  = l & 31;
    int rg = l >> 5;
#pragma unroll
    for (int i = 0; i < 8; ++i) {
        int row = rg * 8 + i;
        float mx = cbq + c0 * hlds[0][row][e] + c1 * hlds[1][row][e]
                       + c2 * hlds[2][row][e] + c3 * hlds[3][row][e];
        float lat = mx >= 0.f ? mx : p1 * mx;
        out[(((size_t)b * R_ + q) * N_ + (n0 + row)) * DOUT + e] = lat;
    }
}

extern "C" void kernel_launch(void* const* d_in, const int* in_sizes, int n_in,
                              void* d_out, int out_size, void* d_ws, size_t ws_size,
                              hipStream_t stream)
{
    const float* theta = (const float*)d_in[0];
    const float* tpar  = (const float*)d_in[1];
    const float* A     = (const float*)d_in[2];
    const float* X     = (const float*)d_in[3];
    const float* fcw   = (const float*)d_in[4];
    const float* fcb   = (const float*)d_in[5];
    const float* cw    = (const float*)d_in[6];
    const float* cb    = (const float*)d_in[7];
    const float* p0    = (const float*)d_in[8];
    const float* p1    = (const float*)d_in[9];

    __hip_bfloat16* xwt = (__hip_bfloat16*)d_ws;   // 4 MiB

    prep_xw<<<B_ * R_ * (N_ / 64), 256, 0, stream>>>(theta, tpar, X, fcw, xwt);
    fused_main<<<B_ * (N_ / 16), 256, 0, stream>>>(A, xwt, fcb, cw, cb, p0, p1,
                                                   (float*)d_out);
}